// Round 2
// baseline (23398.022 us; speedup 1.0000x reference)
//
#include <hip/hip_runtime.h>

#define Bn 4
#define Tn 2048
#define Hn 512
#define En 512
#define Vn 32000
#define G3 1536
#define BT (Bn*Tn)

typedef __bf16 bf16x8 __attribute__((ext_vector_type(8)));
typedef float f32x4 __attribute__((ext_vector_type(4)));

__device__ __forceinline__ unsigned short f2bf(float f) {
  unsigned int u = __float_as_uint(f);
  u += 0x7fffu + ((u >> 16) & 1u);
  return (unsigned short)(u >> 16);
}

// ---------------- fp32 -> bf16 conversion (4 elems/thread, exact grid) -------
__global__ __launch_bounds__(256) void cvt_bf16_kernel(const float* __restrict__ in,
                                                       unsigned short* __restrict__ outp) {
  size_t idx = (size_t)blockIdx.x * 256 + threadIdx.x;
  float4 f = *(const float4*)(in + idx * 4);
  uint2 o;
  o.x = (unsigned int)f2bf(f.x) | ((unsigned int)f2bf(f.y) << 16);
  o.y = (unsigned int)f2bf(f.z) | ((unsigned int)f2bf(f.w) << 16);
  *(uint2*)(outp + idx * 4) = o;
}

// ---------------- xg = emb[x] @ W_ih^T + b_ih  (fp32 tiled, 64x64) -----------
__global__ __launch_bounds__(256) void xg_kernel(const int* __restrict__ x,
                                                 const float* __restrict__ emb,
                                                 const float* __restrict__ Wih,
                                                 const float* __restrict__ bih,
                                                 float* __restrict__ xg) {
  __shared__ float As[64][17];
  __shared__ float Bs[64][17];
  __shared__ int xi[64];
  int tid = threadIdx.x;
  int i0 = blockIdx.y * 64, g0 = blockIdx.x * 64;
  if (tid < 64) xi[tid] = x[i0 + tid];
  __syncthreads();
  int ty = tid >> 4, tx = tid & 15;
  int lr = tid >> 2, lc = (tid & 3) * 4;
  float acc[4][4];
#pragma unroll
  for (int a = 0; a < 4; ++a)
#pragma unroll
    for (int c = 0; c < 4; ++c) acc[a][c] = 0.0f;
  for (int k0 = 0; k0 < En; k0 += 16) {
    float4 av = *(const float4*)(emb + (size_t)xi[lr] * En + k0 + lc);
    float4 bv = *(const float4*)(Wih + (size_t)(g0 + lr) * En + k0 + lc);
    As[lr][lc] = av.x; As[lr][lc+1] = av.y; As[lr][lc+2] = av.z; As[lr][lc+3] = av.w;
    Bs[lr][lc] = bv.x; Bs[lr][lc+1] = bv.y; Bs[lr][lc+2] = bv.z; Bs[lr][lc+3] = bv.w;
    __syncthreads();
#pragma unroll
    for (int kk = 0; kk < 16; ++kk) {
      float a[4], b[4];
#pragma unroll
      for (int ii = 0; ii < 4; ++ii) a[ii] = As[ty*4+ii][kk];
#pragma unroll
      for (int jj = 0; jj < 4; ++jj) b[jj] = Bs[tx*4+jj][kk];
#pragma unroll
      for (int ii = 0; ii < 4; ++ii)
#pragma unroll
        for (int jj = 0; jj < 4; ++jj) acc[ii][jj] += a[ii]*b[jj];
    }
    __syncthreads();
  }
#pragma unroll
  for (int ii = 0; ii < 4; ++ii) {
    int gi = i0 + ty*4 + ii;
#pragma unroll
    for (int jj = 0; jj < 4; ++jj) {
      int gg = g0 + tx*4 + jj;
      xg[(size_t)gi * G3 + gg] = acc[ii][jj] + bih[gg];
    }
  }
}

// ---------------- GRU scan: 64 WGs, each owns 8 hidden units for ALL batches -
// W_hh rows resident in LDS; per-step cross-WG h exchange via device-scope
// release/acquire counter barrier.
__global__ __launch_bounds__(256) void gru_kernel(const float* __restrict__ Whh,
                                                  const float* __restrict__ bhh,
                                                  const float* __restrict__ xg,
                                                  float* __restrict__ hs,
                                                  int* __restrict__ ctr) {
  __shared__ float w_lds[24][512];
  __shared__ float h_lds[4][512];
  __shared__ float dots[4][24];
  __shared__ float bh[24];
  int tid = threadIdx.x;
  int g = blockIdx.x;          // 0..63
  int jb = g * 8;
  for (int d = 0; d < 24; ++d) {
    int gate = d >> 3, u = d & 7;
    const float* wr = Whh + (size_t)(gate*512 + jb + u) * 512;
    w_lds[d][tid]       = wr[tid];
    w_lds[d][tid + 256] = wr[tid + 256];
  }
  if (tid < 24) {
    int gate = tid >> 3, u = tid & 7;
    bh[tid] = bhh[gate*512 + jb + u];
  }
  __syncthreads();
  int w = tid >> 6, lane = tid & 63;
  for (int t = 0; t < Tn; ++t) {
    if (t > 0) {
      if (tid == 0) {
        while (__hip_atomic_load(&ctr[t-1], __ATOMIC_ACQUIRE, __HIP_MEMORY_SCOPE_AGENT) < 64) {
          __builtin_amdgcn_s_sleep(1);
        }
      }
      __syncthreads();
      const float* hp = hs + (size_t)(w*Tn + (t-1)) * Hn;
      float4 h0 = *(const float4*)(hp + lane*8);
      float4 h1 = *(const float4*)(hp + lane*8 + 4);
      *(float4*)&h_lds[w][lane*8]     = h0;
      *(float4*)&h_lds[w][lane*8 + 4] = h1;
    } else {
      for (int s = tid; s < 4*512; s += 256) ((float*)h_lds)[s] = 0.0f;
    }
    __syncthreads();
    // wave w computes the 24 dot products for batch w
    for (int d = 0; d < 24; ++d) {
      float p = 0.0f;
#pragma unroll
      for (int s2 = 0; s2 < 8; ++s2)
        p += w_lds[d][lane + 64*s2] * h_lds[w][lane + 64*s2];
#pragma unroll
      for (int off = 32; off > 0; off >>= 1) p += __shfl_down(p, off);
      if (lane == 0) dots[w][d] = p;
    }
    __syncthreads();
    if (tid < 32) {
      int b = tid >> 3, u = tid & 7;
      size_t xbase = (size_t)(b*Tn + t) * G3 + jb + u;
      float xr = xg[xbase];
      float xz = xg[xbase + 512];
      float xn = xg[xbase + 1024];
      float hr = dots[b][u]      + bh[u];
      float hz = dots[b][8 + u]  + bh[8 + u];
      float hn = dots[b][16 + u] + bh[16 + u];
      float r = 1.0f / (1.0f + expf(-(xr + hr)));
      float z = 1.0f / (1.0f + expf(-(xz + hz)));
      float n = tanhf(xn + r * hn);
      float hp = h_lds[b][jb + u];
      float hnew = (1.0f - z) * n + z * hp;
      hs[(size_t)(b*Tn + t) * Hn + jb + u] = hnew;
    }
    __syncthreads();   // drains the hs stores of all waves (vmcnt(0) before s_barrier)
    if (tid == 0) {
      __threadfence();
      __hip_atomic_fetch_add(&ctr[t], 1, __ATOMIC_RELEASE, __HIP_MEMORY_SCOPE_AGENT);
    }
  }
}

// ---------------- q,k,v = hs @ W{q,k,v}^T + b  (fp32 tiled 64x64) ------------
__global__ __launch_bounds__(256) void qkv_kernel(const float* __restrict__ hs,
                                                  const float* __restrict__ Wq, const float* __restrict__ bq,
                                                  const float* __restrict__ Wk, const float* __restrict__ bk,
                                                  const float* __restrict__ Wv, const float* __restrict__ bv,
                                                  float* __restrict__ q, float* __restrict__ k, float* __restrict__ v) {
  __shared__ float As[64][17];
  __shared__ float Bs[64][17];
  int tid = threadIdx.x;
  int i0 = blockIdx.y * 64, g0 = blockIdx.x * 64;
  int sel = g0 / 512;            // uniform per block
  const float* W    = (sel == 0) ? Wq : (sel == 1) ? Wk : Wv;
  const float* bias = (sel == 0) ? bq : (sel == 1) ? bk : bv;
  float* outp       = (sel == 0) ? q  : (sel == 1) ? k  : v;
  int n0 = g0 % 512;
  int ty = tid >> 4, tx = tid & 15;
  int lr = tid >> 2, lc = (tid & 3) * 4;
  float acc[4][4];
#pragma unroll
  for (int a = 0; a < 4; ++a)
#pragma unroll
    for (int c = 0; c < 4; ++c) acc[a][c] = 0.0f;
  for (int k0 = 0; k0 < Hn; k0 += 16) {
    float4 av = *(const float4*)(hs + (size_t)(i0 + lr) * Hn + k0 + lc);
    float4 bv4 = *(const float4*)(W + (size_t)(n0 + lr) * Hn + k0 + lc);
    As[lr][lc] = av.x; As[lr][lc+1] = av.y; As[lr][lc+2] = av.z; As[lr][lc+3] = av.w;
    Bs[lr][lc] = bv4.x; Bs[lr][lc+1] = bv4.y; Bs[lr][lc+2] = bv4.z; Bs[lr][lc+3] = bv4.w;
    __syncthreads();
#pragma unroll
    for (int kk = 0; kk < 16; ++kk) {
      float a[4], b[4];
#pragma unroll
      for (int ii = 0; ii < 4; ++ii) a[ii] = As[ty*4+ii][kk];
#pragma unroll
      for (int jj = 0; jj < 4; ++jj) b[jj] = Bs[tx*4+jj][kk];
#pragma unroll
      for (int ii = 0; ii < 4; ++ii)
#pragma unroll
        for (int jj = 0; jj < 4; ++jj) acc[ii][jj] += a[ii]*b[jj];
    }
    __syncthreads();
  }
#pragma unroll
  for (int ii = 0; ii < 4; ++ii) {
    int gi = i0 + ty*4 + ii;
#pragma unroll
    for (int jj = 0; jj < 4; ++jj) {
      int nn = n0 + tx*4 + jj;
      outp[(size_t)gi * Hn + nn] = acc[ii][jj] + bias[nn];
    }
  }
}

// ---------------- scores = q @ k^T / sqrt(H), lower-triangular tiles ---------
__global__ __launch_bounds__(256) void score_kernel(const float* __restrict__ q,
                                                    const float* __restrict__ k,
                                                    float* __restrict__ s) {
  int tj = blockIdx.x, ti = blockIdx.y, b = blockIdx.z;
  if (tj > ti) return;
  __shared__ float As[64][17];
  __shared__ float Bs[64][17];
  const float* qb = q + (size_t)b * Tn * Hn;
  const float* kb = k + (size_t)b * Tn * Hn;
  int i0 = ti * 64, j0 = tj * 64;
  int tid = threadIdx.x;
  int ty = tid >> 4, tx = tid & 15;
  int lr = tid >> 2, lc = (tid & 3) * 4;
  float acc[4][4];
#pragma unroll
  for (int a = 0; a < 4; ++a)
#pragma unroll
    for (int c = 0; c < 4; ++c) acc[a][c] = 0.0f;
  for (int k0 = 0; k0 < Hn; k0 += 16) {
    float4 av = *(const float4*)(qb + (size_t)(i0 + lr) * Hn + k0 + lc);
    float4 bv = *(const float4*)(kb + (size_t)(j0 + lr) * Hn + k0 + lc);
    As[lr][lc] = av.x; As[lr][lc+1] = av.y; As[lr][lc+2] = av.z; As[lr][lc+3] = av.w;
    Bs[lr][lc] = bv.x; Bs[lr][lc+1] = bv.y; Bs[lr][lc+2] = bv.z; Bs[lr][lc+3] = bv.w;
    __syncthreads();
#pragma unroll
    for (int kk = 0; kk < 16; ++kk) {
      float a[4], bb[4];
#pragma unroll
      for (int ii = 0; ii < 4; ++ii) a[ii] = As[ty*4+ii][kk];
#pragma unroll
      for (int jj = 0; jj < 4; ++jj) bb[jj] = Bs[tx*4+jj][kk];
#pragma unroll
      for (int ii = 0; ii < 4; ++ii)
#pragma unroll
        for (int jj = 0; jj < 4; ++jj) acc[ii][jj] += a[ii]*bb[jj];
    }
    __syncthreads();
  }
  const float scale = 0.04419417382415922f;  // 1/sqrt(512)
#pragma unroll
  for (int ii = 0; ii < 4; ++ii) {
    int gi = i0 + ty*4 + ii;
#pragma unroll
    for (int jj = 0; jj < 4; ++jj) {
      int gj = j0 + tx*4 + jj;
      s[(size_t)b*Tn*Tn + (size_t)gi*Tn + gj] = acc[ii][jj] * scale;
    }
  }
}

// ---------------- causal softmax in-place over row [0..i] --------------------
__global__ __launch_bounds__(256) void softmax_kernel(float* __restrict__ s) {
  int row = blockIdx.x;
  int b = row >> 11, i = row & 2047;
  float* p = s + (size_t)b*Tn*Tn + (size_t)i*Tn;
  int len = i + 1;
  int tid = threadIdx.x;
  __shared__ float redm[4];
  __shared__ float reds[4];
  float m = -1e30f;
  for (int j = tid; j < len; j += 256) m = fmaxf(m, p[j]);
#pragma unroll
  for (int off = 32; off > 0; off >>= 1) m = fmaxf(m, __shfl_down(m, off));
  if ((tid & 63) == 0) redm[tid >> 6] = m;
  __syncthreads();
  if (tid == 0) redm[0] = fmaxf(fmaxf(redm[0], redm[1]), fmaxf(redm[2], redm[3]));
  __syncthreads();
  m = redm[0];
  float sum = 0.0f;
  for (int j = tid; j < len; j += 256) {
    float e = __expf(p[j] - m);
    p[j] = e;
    sum += e;
  }
#pragma unroll
  for (int off = 32; off > 0; off >>= 1) sum += __shfl_down(sum, off);
  if ((tid & 63) == 0) reds[tid >> 6] = sum;
  __syncthreads();
  if (tid == 0) reds[0] = reds[0] + reds[1] + reds[2] + reds[3];
  __syncthreads();
  float inv = 1.0f / reds[0];
  for (int j = tid; j < len; j += 256) p[j] *= inv;
}

// ---------------- ctx = attn @ v  (causal, fp32 tiled 64x64) -----------------
__global__ __launch_bounds__(256) void ctx_kernel(const float* __restrict__ s,
                                                  const float* __restrict__ v,
                                                  float* __restrict__ ctx) {
  int te = blockIdx.x, ti = blockIdx.y, b = blockIdx.z;
  __shared__ float As[64][17];   // attn[i][j] chunk
  __shared__ float Bs[16][65];   // v[j][e] chunk
  int i0 = ti * 64, e0 = te * 64;
  int kmax = (ti + 1) * 64;
  int tid = threadIdx.x;
  int ty = tid >> 4, tx = tid & 15;
  float acc[4][4];
#pragma unroll
  for (int a = 0; a < 4; ++a)
#pragma unroll
    for (int c = 0; c < 4; ++c) acc[a][c] = 0.0f;
  int lr = tid >> 2, lc = (tid & 3) * 4;      // A-load: 64 rows x 16 cols
  int jr = tid >> 4, ec = (tid & 15) * 4;     // B-load: 16 rows x 64 cols
  for (int k0 = 0; k0 < kmax; k0 += 16) {
    int gi = i0 + lr;
    float4 av = *(const float4*)(s + (size_t)b*Tn*Tn + (size_t)gi*Tn + k0 + lc);
    As[lr][lc]   = (k0 + lc     <= gi) ? av.x : 0.0f;
    As[lr][lc+1] = (k0 + lc + 1 <= gi) ? av.y : 0.0f;
    As[lr][lc+2] = (k0 + lc + 2 <= gi) ? av.z : 0.0f;
    As[lr][lc+3] = (k0 + lc + 3 <= gi) ? av.w : 0.0f;
    float4 bv = *(const float4*)(v + (size_t)b*Tn*Hn + (size_t)(k0 + jr)*Hn + e0 + ec);
    Bs[jr][ec] = bv.x; Bs[jr][ec+1] = bv.y; Bs[jr][ec+2] = bv.z; Bs[jr][ec+3] = bv.w;
    __syncthreads();
#pragma unroll
    for (int kk = 0; kk < 16; ++kk) {
      float a[4], bb[4];
#pragma unroll
      for (int ii = 0; ii < 4; ++ii) a[ii] = As[ty*4+ii][kk];
#pragma unroll
      for (int jj = 0; jj < 4; ++jj) bb[jj] = Bs[kk][tx*4+jj];
#pragma unroll
      for (int ii = 0; ii < 4; ++ii)
#pragma unroll
        for (int jj = 0; jj < 4; ++jj) acc[ii][jj] += a[ii]*bb[jj];
    }
    __syncthreads();
  }
#pragma unroll
  for (int ii = 0; ii < 4; ++ii) {
    int gi = i0 + ty*4 + ii;
#pragma unroll
    for (int jj = 0; jj < 4; ++jj) {
      int ge = e0 + tx*4 + jj;
      ctx[(size_t)(b*Tn + gi) * Hn + ge] = acc[ii][jj];
    }
  }
}

// ---------------- logits = ctx_bf16 @ Wfc_bf16^T + bfc  (MFMA 16x16x32) ------
__global__ __launch_bounds__(256) void logits_kernel(const unsigned short* __restrict__ A,
                                                     const unsigned short* __restrict__ Bw,
                                                     const float* __restrict__ bias,
                                                     float* __restrict__ out) {
  __shared__ unsigned short a_lds[128 * 40];   // 128 rows, 32 cols padded to 40
  __shared__ unsigned short b_lds[128 * 40];
  int n0 = blockIdx.x * 128, m0 = blockIdx.y * 128;
  int tid = threadIdx.x;
  int wid = tid >> 6, lane = tid & 63;
  int wm = wid >> 1, wn = wid & 1;
  f32x4 acc[4][4];
#pragma unroll
  for (int mf = 0; mf < 4; ++mf)
#pragma unroll
    for (int nf = 0; nf < 4; ++nf) {
      acc[mf][nf][0] = 0.0f; acc[mf][nf][1] = 0.0f;
      acc[mf][nf][2] = 0.0f; acc[mf][nf][3] = 0.0f;
    }
  int kcol = (lane >> 4) * 8;
  int rbase = lane & 15;
  for (int k0 = 0; k0 < 512; k0 += 32) {
#pragma unroll
    for (int sidx = 0; sidx < 2; ++sidx) {
      int slot = tid + sidx * 256;              // 512 slots: 128 rows x 4 (8-col groups)
      int row = slot >> 2, c8 = (slot & 3) * 8;
      uint4 av = *(const uint4*)(A  + (size_t)(m0 + row) * 512 + k0 + c8);
      *(uint4*)&a_lds[row * 40 + c8] = av;
      uint4 bv = *(const uint4*)(Bw + (size_t)(n0 + row) * 512 + k0 + c8);
      *(uint4*)&b_lds[row * 40 + c8] = bv;
    }
    __syncthreads();
    bf16x8 af[4], bf[4];
#pragma unroll
    for (int mf = 0; mf < 4; ++mf)
      af[mf] = *(const bf16x8*)&a_lds[(wm*64 + mf*16 + rbase) * 40 + kcol];
#pragma unroll
    for (int nf = 0; nf < 4; ++nf)
      bf[nf] = *(const bf16x8*)&b_lds[(wn*64 + nf*16 + rbase) * 40 + kcol];
#pragma unroll
    for (int mf = 0; mf < 4; ++mf)
#pragma unroll
      for (int nf = 0; nf < 4; ++nf)
        acc[mf][nf] = __builtin_amdgcn_mfma_f32_16x16x32_bf16(af[mf], bf[nf], acc[mf][nf], 0, 0, 0);
    __syncthreads();
  }
  int rgrp = (lane >> 4) * 4;
#pragma unroll
  for (int mf = 0; mf < 4; ++mf)
#pragma unroll
    for (int nf = 0; nf < 4; ++nf) {
      int col = n0 + wn*64 + nf*16 + (lane & 15);
      float bc = bias[col];
#pragma unroll
      for (int i2 = 0; i2 < 4; ++i2) {
        int row = m0 + wm*64 + mf*16 + rgrp + i2;
        out[(size_t)row * Vn + col] = acc[mf][nf][i2] + bc;
      }
    }
}

extern "C" void kernel_launch(void* const* d_in, const int* in_sizes, int n_in,
                              void* d_out, int out_size, void* d_ws, size_t ws_size,
                              hipStream_t stream) {
  const int*   x   = (const int*)d_in[0];
  const float* emb = (const float*)d_in[1];
  const float* Wih = (const float*)d_in[2];
  const float* Whh = (const float*)d_in[3];
  const float* bih = (const float*)d_in[4];
  const float* bhh = (const float*)d_in[5];
  const float* Wq  = (const float*)d_in[6];
  const float* bq  = (const float*)d_in[7];
  const float* Wk  = (const float*)d_in[8];
  const float* bk  = (const float*)d_in[9];
  const float* Wv  = (const float*)d_in[10];
  const float* bv  = (const float*)d_in[11];
  const float* Wfc = (const float*)d_in[12];
  const float* bfc = (const float*)d_in[13];
  float* out = (float*)d_out;

  char* ws = (char*)d_ws;
  float* hs  = (float*)(ws);                                  // 16,777,216 B
  float* q   = (float*)(ws + 16777216);                       // 16,777,216 B
  float* k   = (float*)(ws + 33554432);                       // 16,777,216 B
  float* v   = (float*)(ws + 50331648);                       // 16,777,216 B
  float* ctx = (float*)(ws + 67108864);                       // 16,777,216 B
  unsigned short* ctxb = (unsigned short*)(ws + 83886080);    //  8,388,608 B
  unsigned short* wfcb = (unsigned short*)(ws + 92274688);    // 32,768,000 B
  int* ctr = (int*)(ws + 125042688);                          //      8,192 B
  // ws total: 125,050,880 B

  // d_out (1,048,576,000 B) doubles as scratch for scores + xg, both fully
  // consumed before logits_kernel overwrites the whole buffer.
  float* scores = out;                                        // 67,108,864 B
  float* xg = (float*)((char*)d_out + 67108864);              // 50,331,648 B

  hipMemsetAsync(ctr, 0, Tn * sizeof(int), stream);
  cvt_bf16_kernel<<<16000, 256, 0, stream>>>(Wfc, wfcb);                       // 16,384,000 elems
  xg_kernel<<<dim3(24, 128), 256, 0, stream>>>(x, emb, Wih, bih, xg);
  gru_kernel<<<64, 256, 0, stream>>>(Whh, bhh, xg, hs, ctr);
  qkv_kernel<<<dim3(24, 128), 256, 0, stream>>>(hs, Wq, bq, Wk, bk, Wv, bv, q, k, v);
  score_kernel<<<dim3(32, 32, Bn), 256, 0, stream>>>(q, k, scores);
  softmax_kernel<<<BT, 256, 0, stream>>>(scores);
  ctx_kernel<<<dim3(8, 32, Bn), 256, 0, stream>>>(scores, v, ctx);
  cvt_bf16_kernel<<<4096, 256, 0, stream>>>(ctx, ctxb);                        // 4,194,304 elems
  logits_kernel<<<dim3(250, 64), 256, 0, stream>>>(ctxb, wfcb, bfc, out);
}

// Round 3
// 18541.670 us; speedup vs baseline: 1.2619x; 1.2619x over previous
//
#include <hip/hip_runtime.h>

#define Bn 4
#define Tn 2048
#define Hn 512
#define En 512
#define Vn 32000
#define G3 1536
#define BT (Bn*Tn)

typedef __bf16 bf16x8 __attribute__((ext_vector_type(8)));
typedef float f32x4 __attribute__((ext_vector_type(4)));

__device__ __forceinline__ unsigned short f2bf(float f) {
  unsigned int u = __float_as_uint(f);
  u += 0x7fffu + ((u >> 16) & 1u);
  return (unsigned short)(u >> 16);
}

// ---------------- fp32 -> bf16 conversion (4 elems/thread, exact grid) -------
__global__ __launch_bounds__(256) void cvt_bf16_kernel(const float* __restrict__ in,
                                                       unsigned short* __restrict__ outp) {
  size_t idx = (size_t)blockIdx.x * 256 + threadIdx.x;
  float4 f = *(const float4*)(in + idx * 4);
  uint2 o;
  o.x = (unsigned int)f2bf(f.x) | ((unsigned int)f2bf(f.y) << 16);
  o.y = (unsigned int)f2bf(f.z) | ((unsigned int)f2bf(f.w) << 16);
  *(uint2*)(outp + idx * 4) = o;
}

// ---------------- xg = emb[x] @ W_ih^T + b_ih  (fp32 tiled, 64x64) -----------
__global__ __launch_bounds__(256) void xg_kernel(const int* __restrict__ x,
                                                 const float* __restrict__ emb,
                                                 const float* __restrict__ Wih,
                                                 const float* __restrict__ bih,
                                                 float* __restrict__ xg) {
  __shared__ float As[64][17];
  __shared__ float Bs[64][17];
  __shared__ int xi[64];
  int tid = threadIdx.x;
  int i0 = blockIdx.y * 64, g0 = blockIdx.x * 64;
  if (tid < 64) xi[tid] = x[i0 + tid];
  __syncthreads();
  int ty = tid >> 4, tx = tid & 15;
  int lr = tid >> 2, lc = (tid & 3) * 4;
  float acc[4][4];
#pragma unroll
  for (int a = 0; a < 4; ++a)
#pragma unroll
    for (int c = 0; c < 4; ++c) acc[a][c] = 0.0f;
  for (int k0 = 0; k0 < En; k0 += 16) {
    float4 av = *(const float4*)(emb + (size_t)xi[lr] * En + k0 + lc);
    float4 bv = *(const float4*)(Wih + (size_t)(g0 + lr) * En + k0 + lc);
    As[lr][lc] = av.x; As[lr][lc+1] = av.y; As[lr][lc+2] = av.z; As[lr][lc+3] = av.w;
    Bs[lr][lc] = bv.x; Bs[lr][lc+1] = bv.y; Bs[lr][lc+2] = bv.z; Bs[lr][lc+3] = bv.w;
    __syncthreads();
#pragma unroll
    for (int kk = 0; kk < 16; ++kk) {
      float a[4], b[4];
#pragma unroll
      for (int ii = 0; ii < 4; ++ii) a[ii] = As[ty*4+ii][kk];
#pragma unroll
      for (int jj = 0; jj < 4; ++jj) b[jj] = Bs[tx*4+jj][kk];
#pragma unroll
      for (int ii = 0; ii < 4; ++ii)
#pragma unroll
        for (int jj = 0; jj < 4; ++jj) acc[ii][jj] += a[ii]*b[jj];
    }
    __syncthreads();
  }
#pragma unroll
  for (int ii = 0; ii < 4; ++ii) {
    int gi = i0 + ty*4 + ii;
#pragma unroll
    for (int jj = 0; jj < 4; ++jj) {
      int gg = g0 + tx*4 + jj;
      xg[(size_t)gi * G3 + gg] = acc[ii][jj] + bih[gg];
    }
  }
}

// ---------------- GRU scan: 64 WGs, each owns 8 hidden units for ALL batches -
// W_hh rows REGISTER-resident; cross-WG h exchange entirely via device-scope
// RELAXED atomics (write-through to LLC, no L2 flush/inv fences) + per-WG flag
// array (no RMW contention).
__global__ __launch_bounds__(256, 1) void gru_kernel(const float* __restrict__ Whh,
                                                     const float* __restrict__ bhh,
                                                     const float* __restrict__ xg,
                                                     float* __restrict__ hs,
                                                     int* __restrict__ flags) {
  __shared__ float dots[4][24];
  __shared__ float bh[24];
  __shared__ float h_own[4][8];
  int tid = threadIdx.x;
  int g = blockIdx.x;          // 0..63
  int jb = g * 8;
  int w = tid >> 6, lane = tid & 63;

  // wreg[d][s] = Whh[(gate*512 + jb + u)][s*64 + lane], d = gate*8 + u
  float wreg[24][8];
#pragma unroll
  for (int d = 0; d < 24; ++d) {
    const float* wr = Whh + (size_t)((d >> 3) * 512 + jb + (d & 7)) * 512;
#pragma unroll
    for (int s = 0; s < 8; ++s) wreg[d][s] = wr[s * 64 + lane];
  }
  if (tid < 24) bh[tid] = bhh[(tid >> 3) * 512 + jb + (tid & 7)];
  if (tid < 32) h_own[tid >> 3][tid & 7] = 0.0f;
  __syncthreads();

  for (int t = 0; t < Tn; ++t) {
    // prefetch x-gates early so the loads fly during the poll
    float xr, xz, xn;
    if (tid < 32) {
      int b = tid >> 3, u = tid & 7;
      size_t xbase = ((size_t)(b * Tn + t)) * G3 + jb + u;
      xr = xg[xbase]; xz = xg[xbase + 512]; xn = xg[xbase + 1024];
    }
    float hreg[8];
    if (t > 0) {
      if (w == 0) {
        int v;
        do {
          v = __hip_atomic_load(&flags[lane], __ATOMIC_RELAXED, __HIP_MEMORY_SCOPE_AGENT);
        } while (__any(v < t));
      }
      __syncthreads();
      const float* hp = hs + ((size_t)w * Tn + (t - 1)) * Hn;
#pragma unroll
      for (int s = 0; s < 8; ++s)
        hreg[s] = __hip_atomic_load(hp + s * 64 + lane, __ATOMIC_RELAXED, __HIP_MEMORY_SCOPE_AGENT);
    } else {
#pragma unroll
      for (int s = 0; s < 8; ++s) hreg[s] = 0.0f;
    }
    // 24 dot products for batch w, all register-resident
#pragma unroll
    for (int d = 0; d < 24; ++d) {
      float p = wreg[d][0] * hreg[0];
#pragma unroll
      for (int s = 1; s < 8; ++s) p = fmaf(wreg[d][s], hreg[s], p);
#pragma unroll
      for (int off = 32; off > 0; off >>= 1) p += __shfl_down(p, off);
      if (lane == 0) dots[w][d] = p;
    }
    __syncthreads();
    if (tid < 32) {
      int b = tid >> 3, u = tid & 7;
      float r = 1.0f / (1.0f + __expf(-(xr + dots[b][u] + bh[u])));
      float z = 1.0f / (1.0f + __expf(-(xz + dots[b][8 + u] + bh[8 + u])));
      float n = tanhf(xn + r * (dots[b][16 + u] + bh[16 + u]));
      float hnew = (1.0f - z) * n + z * h_own[b][u];
      h_own[b][u] = hnew;
      __hip_atomic_store(hs + ((size_t)b * Tn + t) * Hn + jb + u, hnew,
                         __ATOMIC_RELAXED, __HIP_MEMORY_SCOPE_AGENT);
    }
    // drain this wave's stores (they are write-through agent-scope), then flag
    asm volatile("s_waitcnt vmcnt(0)" ::: "memory");
    if (tid == 0)
      __hip_atomic_store(&flags[g], t + 1, __ATOMIC_RELAXED, __HIP_MEMORY_SCOPE_AGENT);
  }
}

// ---------------- q,k,v = hs @ W{q,k,v}^T + b  (fp32 tiled 64x64) ------------
__global__ __launch_bounds__(256) void qkv_kernel(const float* __restrict__ hs,
                                                  const float* __restrict__ Wq, const float* __restrict__ bq,
                                                  const float* __restrict__ Wk, const float* __restrict__ bk,
                                                  const float* __restrict__ Wv, const float* __restrict__ bv,
                                                  float* __restrict__ q, float* __restrict__ k, float* __restrict__ v) {
  __shared__ float As[64][17];
  __shared__ float Bs[64][17];
  int tid = threadIdx.x;
  int i0 = blockIdx.y * 64, g0 = blockIdx.x * 64;
  int sel = g0 / 512;            // uniform per block
  const float* W    = (sel == 0) ? Wq : (sel == 1) ? Wk : Wv;
  const float* bias = (sel == 0) ? bq : (sel == 1) ? bk : bv;
  float* outp       = (sel == 0) ? q  : (sel == 1) ? k  : v;
  int n0 = g0 % 512;
  int ty = tid >> 4, tx = tid & 15;
  int lr = tid >> 2, lc = (tid & 3) * 4;
  float acc[4][4];
#pragma unroll
  for (int a = 0; a < 4; ++a)
#pragma unroll
    for (int c = 0; c < 4; ++c) acc[a][c] = 0.0f;
  for (int k0 = 0; k0 < Hn; k0 += 16) {
    float4 av = *(const float4*)(hs + (size_t)(i0 + lr) * Hn + k0 + lc);
    float4 bv4 = *(const float4*)(W + (size_t)(n0 + lr) * Hn + k0 + lc);
    As[lr][lc] = av.x; As[lr][lc+1] = av.y; As[lr][lc+2] = av.z; As[lr][lc+3] = av.w;
    Bs[lr][lc] = bv4.x; Bs[lr][lc+1] = bv4.y; Bs[lr][lc+2] = bv4.z; Bs[lr][lc+3] = bv4.w;
    __syncthreads();
#pragma unroll
    for (int kk = 0; kk < 16; ++kk) {
      float a[4], b[4];
#pragma unroll
      for (int ii = 0; ii < 4; ++ii) a[ii] = As[ty*4+ii][kk];
#pragma unroll
      for (int jj = 0; jj < 4; ++jj) b[jj] = Bs[tx*4+jj][kk];
#pragma unroll
      for (int ii = 0; ii < 4; ++ii)
#pragma unroll
        for (int jj = 0; jj < 4; ++jj) acc[ii][jj] += a[ii]*b[jj];
    }
    __syncthreads();
  }
#pragma unroll
  for (int ii = 0; ii < 4; ++ii) {
    int gi = i0 + ty*4 + ii;
#pragma unroll
    for (int jj = 0; jj < 4; ++jj) {
      int nn = n0 + tx*4 + jj;
      outp[(size_t)gi * Hn + nn] = acc[ii][jj] + bias[nn];
    }
  }
}

// ---------------- scores = q @ k^T / sqrt(H), lower-triangular tiles ---------
__global__ __launch_bounds__(256) void score_kernel(const float* __restrict__ q,
                                                    const float* __restrict__ k,
                                                    float* __restrict__ s) {
  int tj = blockIdx.x, ti = blockIdx.y, b = blockIdx.z;
  if (tj > ti) return;
  __shared__ float As[64][17];
  __shared__ float Bs[64][17];
  const float* qb = q + (size_t)b * Tn * Hn;
  const float* kb = k + (size_t)b * Tn * Hn;
  int i0 = ti * 64, j0 = tj * 64;
  int tid = threadIdx.x;
  int ty = tid >> 4, tx = tid & 15;
  int lr = tid >> 2, lc = (tid & 3) * 4;
  float acc[4][4];
#pragma unroll
  for (int a = 0; a < 4; ++a)
#pragma unroll
    for (int c = 0; c < 4; ++c) acc[a][c] = 0.0f;
  for (int k0 = 0; k0 < Hn; k0 += 16) {
    float4 av = *(const float4*)(qb + (size_t)(i0 + lr) * Hn + k0 + lc);
    float4 bv = *(const float4*)(kb + (size_t)(j0 + lr) * Hn + k0 + lc);
    As[lr][lc] = av.x; As[lr][lc+1] = av.y; As[lr][lc+2] = av.z; As[lr][lc+3] = av.w;
    Bs[lr][lc] = bv.x; Bs[lr][lc+1] = bv.y; Bs[lr][lc+2] = bv.z; Bs[lr][lc+3] = bv.w;
    __syncthreads();
#pragma unroll
    for (int kk = 0; kk < 16; ++kk) {
      float a[4], bb[4];
#pragma unroll
      for (int ii = 0; ii < 4; ++ii) a[ii] = As[ty*4+ii][kk];
#pragma unroll
      for (int jj = 0; jj < 4; ++jj) bb[jj] = Bs[tx*4+jj][kk];
#pragma unroll
      for (int ii = 0; ii < 4; ++ii)
#pragma unroll
        for (int jj = 0; jj < 4; ++jj) acc[ii][jj] += a[ii]*bb[jj];
    }
    __syncthreads();
  }
  const float scale = 0.04419417382415922f;  // 1/sqrt(512)
#pragma unroll
  for (int ii = 0; ii < 4; ++ii) {
    int gi = i0 + ty*4 + ii;
#pragma unroll
    for (int jj = 0; jj < 4; ++jj) {
      int gj = j0 + tx*4 + jj;
      s[(size_t)b*Tn*Tn + (size_t)gi*Tn + gj] = acc[ii][jj] * scale;
    }
  }
}

// ---------------- causal softmax in-place over row [0..i] --------------------
__global__ __launch_bounds__(256) void softmax_kernel(float* __restrict__ s) {
  int row = blockIdx.x;
  int b = row >> 11, i = row & 2047;
  float* p = s + (size_t)b*Tn*Tn + (size_t)i*Tn;
  int len = i + 1;
  int tid = threadIdx.x;
  __shared__ float redm[4];
  __shared__ float reds[4];
  float m = -1e30f;
  for (int j = tid; j < len; j += 256) m = fmaxf(m, p[j]);
#pragma unroll
  for (int off = 32; off > 0; off >>= 1) m = fmaxf(m, __shfl_down(m, off));
  if ((tid & 63) == 0) redm[tid >> 6] = m;
  __syncthreads();
  if (tid == 0) redm[0] = fmaxf(fmaxf(redm[0], redm[1]), fmaxf(redm[2], redm[3]));
  __syncthreads();
  m = redm[0];
  float sum = 0.0f;
  for (int j = tid; j < len; j += 256) {
    float e = __expf(p[j] - m);
    p[j] = e;
    sum += e;
  }
#pragma unroll
  for (int off = 32; off > 0; off >>= 1) sum += __shfl_down(sum, off);
  if ((tid & 63) == 0) reds[tid >> 6] = sum;
  __syncthreads();
  if (tid == 0) reds[0] = reds[0] + reds[1] + reds[2] + reds[3];
  __syncthreads();
  float inv = 1.0f / reds[0];
  for (int j = tid; j < len; j += 256) p[j] *= inv;
}

// ---------------- ctx = attn @ v  (causal, fp32 tiled 64x64) -----------------
__global__ __launch_bounds__(256) void ctx_kernel(const float* __restrict__ s,
                                                  const float* __restrict__ v,
                                                  float* __restrict__ ctx) {
  int te = blockIdx.x, ti = blockIdx.y, b = blockIdx.z;
  __shared__ float As[64][17];   // attn[i][j] chunk
  __shared__ float Bs[16][65];   // v[j][e] chunk
  int i0 = ti * 64, e0 = te * 64;
  int kmax = (ti + 1) * 64;
  int tid = threadIdx.x;
  int ty = tid >> 4, tx = tid & 15;
  float acc[4][4];
#pragma unroll
  for (int a = 0; a < 4; ++a)
#pragma unroll
    for (int c = 0; c < 4; ++c) acc[a][c] = 0.0f;
  int lr = tid >> 2, lc = (tid & 3) * 4;      // A-load: 64 rows x 16 cols
  int jr = tid >> 4, ec = (tid & 15) * 4;     // B-load: 16 rows x 64 cols
  for (int k0 = 0; k0 < kmax; k0 += 16) {
    int gi = i0 + lr;
    float4 av = *(const float4*)(s + (size_t)b*Tn*Tn + (size_t)gi*Tn + k0 + lc);
    As[lr][lc]   = (k0 + lc     <= gi) ? av.x : 0.0f;
    As[lr][lc+1] = (k0 + lc + 1 <= gi) ? av.y : 0.0f;
    As[lr][lc+2] = (k0 + lc + 2 <= gi) ? av.z : 0.0f;
    As[lr][lc+3] = (k0 + lc + 3 <= gi) ? av.w : 0.0f;
    float4 bv = *(const float4*)(v + (size_t)b*Tn*Hn + (size_t)(k0 + jr)*Hn + e0 + ec);
    Bs[jr][ec] = bv.x; Bs[jr][ec+1] = bv.y; Bs[jr][ec+2] = bv.z; Bs[jr][ec+3] = bv.w;
    __syncthreads();
#pragma unroll
    for (int kk = 0; kk < 16; ++kk) {
      float a[4], bb[4];
#pragma unroll
      for (int ii = 0; ii < 4; ++ii) a[ii] = As[ty*4+ii][kk];
#pragma unroll
      for (int jj = 0; jj < 4; ++jj) bb[jj] = Bs[kk][tx*4+jj];
#pragma unroll
      for (int ii = 0; ii < 4; ++ii)
#pragma unroll
        for (int jj = 0; jj < 4; ++jj) acc[ii][jj] += a[ii]*bb[jj];
    }
    __syncthreads();
  }
#pragma unroll
  for (int ii = 0; ii < 4; ++ii) {
    int gi = i0 + ty*4 + ii;
#pragma unroll
    for (int jj = 0; jj < 4; ++jj) {
      int ge = e0 + tx*4 + jj;
      ctx[(size_t)(b*Tn + gi) * Hn + ge] = acc[ii][jj];
    }
  }
}

// ---------------- logits = ctx_bf16 @ Wfc_bf16^T + bfc  (MFMA 16x16x32) ------
__global__ __launch_bounds__(256) void logits_kernel(const unsigned short* __restrict__ A,
                                                     const unsigned short* __restrict__ Bw,
                                                     const float* __restrict__ bias,
                                                     float* __restrict__ out) {
  __shared__ unsigned short a_lds[128 * 40];   // 128 rows, 32 cols padded to 40
  __shared__ unsigned short b_lds[128 * 40];
  int n0 = blockIdx.x * 128, m0 = blockIdx.y * 128;
  int tid = threadIdx.x;
  int wid = tid >> 6, lane = tid & 63;
  int wm = wid >> 1, wn = wid & 1;
  f32x4 acc[4][4];
#pragma unroll
  for (int mf = 0; mf < 4; ++mf)
#pragma unroll
    for (int nf = 0; nf < 4; ++nf) {
      acc[mf][nf][0] = 0.0f; acc[mf][nf][1] = 0.0f;
      acc[mf][nf][2] = 0.0f; acc[mf][nf][3] = 0.0f;
    }
  int kcol = (lane >> 4) * 8;
  int rbase = lane & 15;
  for (int k0 = 0; k0 < 512; k0 += 32) {
#pragma unroll
    for (int sidx = 0; sidx < 2; ++sidx) {
      int slot = tid + sidx * 256;              // 512 slots: 128 rows x 4 (8-col groups)
      int row = slot >> 2, c8 = (slot & 3) * 8;
      uint4 av = *(const uint4*)(A  + (size_t)(m0 + row) * 512 + k0 + c8);
      *(uint4*)&a_lds[row * 40 + c8] = av;
      uint4 bv = *(const uint4*)(Bw + (size_t)(n0 + row) * 512 + k0 + c8);
      *(uint4*)&b_lds[row * 40 + c8] = bv;
    }
    __syncthreads();
    bf16x8 af[4], bf[4];
#pragma unroll
    for (int mf = 0; mf < 4; ++mf)
      af[mf] = *(const bf16x8*)&a_lds[(wm*64 + mf*16 + rbase) * 40 + kcol];
#pragma unroll
    for (int nf = 0; nf < 4; ++nf)
      bf[nf] = *(const bf16x8*)&b_lds[(wn*64 + nf*16 + rbase) * 40 + kcol];
#pragma unroll
    for (int mf = 0; mf < 4; ++mf)
#pragma unroll
      for (int nf = 0; nf < 4; ++nf)
        acc[mf][nf] = __builtin_amdgcn_mfma_f32_16x16x32_bf16(af[mf], bf[nf], acc[mf][nf], 0, 0, 0);
    __syncthreads();
  }
  int rgrp = (lane >> 4) * 4;
#pragma unroll
  for (int mf = 0; mf < 4; ++mf)
#pragma unroll
    for (int nf = 0; nf < 4; ++nf) {
      int col = n0 + wn*64 + nf*16 + (lane & 15);
      float bc = bias[col];
#pragma unroll
      for (int i2 = 0; i2 < 4; ++i2) {
        int row = m0 + wm*64 + mf*16 + rgrp + i2;
        out[(size_t)row * Vn + col] = acc[mf][nf][i2] + bc;
      }
    }
}

extern "C" void kernel_launch(void* const* d_in, const int* in_sizes, int n_in,
                              void* d_out, int out_size, void* d_ws, size_t ws_size,
                              hipStream_t stream) {
  const int*   x   = (const int*)d_in[0];
  const float* emb = (const float*)d_in[1];
  const float* Wih = (const float*)d_in[2];
  const float* Whh = (const float*)d_in[3];
  const float* bih = (const float*)d_in[4];
  const float* bhh = (const float*)d_in[5];
  const float* Wq  = (const float*)d_in[6];
  const float* bq  = (const float*)d_in[7];
  const float* Wk  = (const float*)d_in[8];
  const float* bk  = (const float*)d_in[9];
  const float* Wv  = (const float*)d_in[10];
  const float* bv  = (const float*)d_in[11];
  const float* Wfc = (const float*)d_in[12];
  const float* bfc = (const float*)d_in[13];
  float* out = (float*)d_out;

  char* ws = (char*)d_ws;
  float* hs  = (float*)(ws);                                  // 16,777,216 B
  float* q   = (float*)(ws + 16777216);                       // 16,777,216 B
  float* k   = (float*)(ws + 33554432);                       // 16,777,216 B
  float* v   = (float*)(ws + 50331648);                       // 16,777,216 B
  float* ctx = (float*)(ws + 67108864);                       // 16,777,216 B
  unsigned short* ctxb = (unsigned short*)(ws + 83886080);    //  8,388,608 B
  unsigned short* wfcb = (unsigned short*)(ws + 92274688);    // 32,768,000 B
  int* flags = (int*)(ws + 125042688);                        //        256 B
  // ws total: ~125 MB

  // d_out (1,048,576,000 B) doubles as scratch for scores + xg, both fully
  // consumed before logits_kernel overwrites the whole buffer.
  float* scores = out;                                        // 67,108,864 B
  float* xg = (float*)((char*)d_out + 67108864);              // 50,331,648 B

  hipMemsetAsync(flags, 0, 64 * sizeof(int), stream);
  cvt_bf16_kernel<<<16000, 256, 0, stream>>>(Wfc, wfcb);                       // 16,384,000 elems
  xg_kernel<<<dim3(24, 128), 256, 0, stream>>>(x, emb, Wih, bih, xg);
  gru_kernel<<<64, 256, 0, stream>>>(Whh, bhh, xg, hs, flags);
  qkv_kernel<<<dim3(24, 128), 256, 0, stream>>>(hs, Wq, bq, Wk, bk, Wv, bv, q, k, v);
  score_kernel<<<dim3(32, 32, Bn), 256, 0, stream>>>(q, k, scores);
  softmax_kernel<<<BT, 256, 0, stream>>>(scores);
  ctx_kernel<<<dim3(8, 32, Bn), 256, 0, stream>>>(scores, v, ctx);
  cvt_bf16_kernel<<<4096, 256, 0, stream>>>(ctx, ctxb);                        // 4,194,304 elems
  logits_kernel<<<dim3(250, 64), 256, 0, stream>>>(ctxb, wfcb, bfc, out);
}

// Round 4
// 8001.769 us; speedup vs baseline: 2.9241x; 2.3172x over previous
//
#include <hip/hip_runtime.h>

#define Bn 4
#define Tn 2048
#define Hn 512
#define En 512
#define Vn 32000
#define G3 1536
#define BT (Bn*Tn)

typedef __bf16 bf16x8 __attribute__((ext_vector_type(8)));
typedef float f32x4 __attribute__((ext_vector_type(4)));

__device__ __forceinline__ unsigned short f2bf(float f) {
  unsigned int u = __float_as_uint(f);
  u += 0x7fffu + ((u >> 16) & 1u);
  return (unsigned short)(u >> 16);
}

// ---------------- fp32 -> bf16 conversion (4 elems/thread, exact grid) -------
__global__ __launch_bounds__(256) void cvt_bf16_kernel(const float* __restrict__ in,
                                                       unsigned short* __restrict__ outp) {
  size_t idx = (size_t)blockIdx.x * 256 + threadIdx.x;
  float4 f = *(const float4*)(in + idx * 4);
  uint2 o;
  o.x = (unsigned int)f2bf(f.x) | ((unsigned int)f2bf(f.y) << 16);
  o.y = (unsigned int)f2bf(f.z) | ((unsigned int)f2bf(f.w) << 16);
  *(uint2*)(outp + idx * 4) = o;
}

// ---------------- xg = emb[x] @ W_ih^T + b_ih  (fp32 tiled, 64x64) -----------
__global__ __launch_bounds__(256) void xg_kernel(const int* __restrict__ x,
                                                 const float* __restrict__ emb,
                                                 const float* __restrict__ Wih,
                                                 const float* __restrict__ bih,
                                                 float* __restrict__ xg) {
  __shared__ float As[64][17];
  __shared__ float Bs[64][17];
  __shared__ int xi[64];
  int tid = threadIdx.x;
  int i0 = blockIdx.y * 64, g0 = blockIdx.x * 64;
  if (tid < 64) xi[tid] = x[i0 + tid];
  __syncthreads();
  int ty = tid >> 4, tx = tid & 15;
  int lr = tid >> 2, lc = (tid & 3) * 4;
  float acc[4][4];
#pragma unroll
  for (int a = 0; a < 4; ++a)
#pragma unroll
    for (int c = 0; c < 4; ++c) acc[a][c] = 0.0f;
  for (int k0 = 0; k0 < En; k0 += 16) {
    float4 av = *(const float4*)(emb + (size_t)xi[lr] * En + k0 + lc);
    float4 bv = *(const float4*)(Wih + (size_t)(g0 + lr) * En + k0 + lc);
    As[lr][lc] = av.x; As[lr][lc+1] = av.y; As[lr][lc+2] = av.z; As[lr][lc+3] = av.w;
    Bs[lr][lc] = bv.x; Bs[lr][lc+1] = bv.y; Bs[lr][lc+2] = bv.z; Bs[lr][lc+3] = bv.w;
    __syncthreads();
#pragma unroll
    for (int kk = 0; kk < 16; ++kk) {
      float a[4], b[4];
#pragma unroll
      for (int ii = 0; ii < 4; ++ii) a[ii] = As[ty*4+ii][kk];
#pragma unroll
      for (int jj = 0; jj < 4; ++jj) b[jj] = Bs[tx*4+jj][kk];
#pragma unroll
      for (int ii = 0; ii < 4; ++ii)
#pragma unroll
        for (int jj = 0; jj < 4; ++jj) acc[ii][jj] += a[ii]*b[jj];
    }
    __syncthreads();
  }
#pragma unroll
  for (int ii = 0; ii < 4; ++ii) {
    int gi = i0 + ty*4 + ii;
#pragma unroll
    for (int jj = 0; jj < 4; ++jj) {
      int gg = g0 + tx*4 + jj;
      xg[(size_t)gi * G3 + gg] = acc[ii][jj] + bih[gg];
    }
  }
}

// ---------------- GRU scan, tagged-value sync ------------------------------
// 64 WGs x 256 thr; wave w of each WG owns batch w. WG g owns hidden units
// [g*8, g*8+8). Cross-WG h exchange: each h element is an 8-byte
// {tag=t+1, value} packed word, stored/loaded with relaxed AGENT atomics.
// Consumers poll the data directly -> no flags, no store-drain, no barriers.
__global__ __launch_bounds__(256, 1) void gru_kernel(const float* __restrict__ Whh,
                                                     const float* __restrict__ bhh,
                                                     const float* __restrict__ xg,
                                                     float* __restrict__ hs,
                                                     unsigned long long* __restrict__ th) {
  __shared__ float red[4][8][24];
  int tid = threadIdx.x;
  int g = blockIdx.x;          // 0..63
  int jb = g * 8;
  int w = tid >> 6, lane = tid & 63;
  int u = lane & 7, grp = lane >> 3;

  // wreg[d][s] = Whh[(gate*512 + jb + u')][s*64 + lane], d = gate*8 + u'
  // loaded via workgroup-scope atomic loads so the compiler cannot
  // rematerialize them inside the t-loop (keeps them VGPR-resident).
  float wreg[24][8];
#pragma unroll
  for (int d = 0; d < 24; ++d) {
    const float* wr = Whh + (size_t)((d >> 3) * 512 + jb + (d & 7)) * 512;
#pragma unroll
    for (int s = 0; s < 8; ++s)
      wreg[d][s] = __hip_atomic_load(wr + s * 64 + lane, __ATOMIC_RELAXED,
                                     __HIP_MEMORY_SCOPE_WORKGROUP);
  }
  float bh_r = bhh[jb + u];
  float bh_z = bhh[512 + jb + u];
  float bh_n = bhh[1024 + jb + u];
  float hown = 0.0f;

  for (int t = 0; t < Tn; ++t) {
    // x-gate loads issue early (independent of the poll)
    size_t xb = ((size_t)(w * Tn + t)) * G3 + jb + u;
    float xr = xg[xb], xz = xg[xb + 512], xn = xg[xb + 1024];

    float hreg[8];
    if (t > 0) {
      const unsigned long long* tp = th + (size_t)(t - 1) * 2048 + w * 512;
      unsigned long long v[8];
      bool rdy;
      do {
        rdy = true;
#pragma unroll
        for (int s = 0; s < 8; ++s)
          v[s] = __hip_atomic_load(tp + s * 64 + lane, __ATOMIC_RELAXED,
                                   __HIP_MEMORY_SCOPE_AGENT);
#pragma unroll
        for (int s = 0; s < 8; ++s)
          rdy = rdy && ((unsigned)(v[s] >> 32) == (unsigned)t);
      } while (!rdy);
#pragma unroll
      for (int s = 0; s < 8; ++s) hreg[s] = __uint_as_float((unsigned)v[s]);
    } else {
#pragma unroll
      for (int s = 0; s < 8; ++s) hreg[s] = 0.0f;
    }

    // 24 row-dots: per-lane partials, 3-level xor reduce within 8-lane groups
    float pd[24];
#pragma unroll
    for (int d = 0; d < 24; ++d) {
      float p = wreg[d][0] * hreg[0];
#pragma unroll
      for (int s = 1; s < 8; ++s) p = fmaf(wreg[d][s], hreg[s], p);
      p += __shfl_xor(p, 1);
      p += __shfl_xor(p, 2);
      p += __shfl_xor(p, 4);
      pd[d] = p;
    }
    if (u == 0) {
#pragma unroll
      for (int d = 0; d < 24; ++d) red[w][grp][d] = pd[d];
    }
    asm volatile("s_waitcnt lgkmcnt(0)" ::: "memory");
    __builtin_amdgcn_sched_barrier(0);
    if (lane < 8) {
      float dr = 0.0f, dz = 0.0f, dn = 0.0f;
#pragma unroll
      for (int gg = 0; gg < 8; ++gg) {
        dr += red[w][gg][u];
        dz += red[w][gg][8 + u];
        dn += red[w][gg][16 + u];
      }
      float r = 1.0f / (1.0f + __expf(-(xr + dr + bh_r)));
      float z = 1.0f / (1.0f + __expf(-(xz + dz + bh_z)));
      float n = tanhf(xn + r * (dn + bh_n));
      hown = (1.0f - z) * n + z * hown;
      unsigned long long pk =
          ((unsigned long long)(unsigned)(t + 1) << 32) |
          (unsigned long long)__float_as_uint(hown);
      __hip_atomic_store(th + (size_t)t * 2048 + w * 512 + jb + u, pk,
                         __ATOMIC_RELAXED, __HIP_MEMORY_SCOPE_AGENT);
      hs[((size_t)w * Tn + t) * Hn + jb + u] = hown;
    }
  }
}

// ---------------- q,k,v = hs @ W{q,k,v}^T + b  (fp32 tiled 64x64) ------------
__global__ __launch_bounds__(256) void qkv_kernel(const float* __restrict__ hs,
                                                  const float* __restrict__ Wq, const float* __restrict__ bq,
                                                  const float* __restrict__ Wk, const float* __restrict__ bk,
                                                  const float* __restrict__ Wv, const float* __restrict__ bv,
                                                  float* __restrict__ q, float* __restrict__ k, float* __restrict__ v) {
  __shared__ float As[64][17];
  __shared__ float Bs[64][17];
  int tid = threadIdx.x;
  int i0 = blockIdx.y * 64, g0 = blockIdx.x * 64;
  int sel = g0 / 512;            // uniform per block
  const float* W    = (sel == 0) ? Wq : (sel == 1) ? Wk : Wv;
  const float* bias = (sel == 0) ? bq : (sel == 1) ? bk : bv;
  float* outp       = (sel == 0) ? q  : (sel == 1) ? k  : v;
  int n0 = g0 % 512;
  int ty = tid >> 4, tx = tid & 15;
  int lr = tid >> 2, lc = (tid & 3) * 4;
  float acc[4][4];
#pragma unroll
  for (int a = 0; a < 4; ++a)
#pragma unroll
    for (int c = 0; c < 4; ++c) acc[a][c] = 0.0f;
  for (int k0 = 0; k0 < Hn; k0 += 16) {
    float4 av = *(const float4*)(hs + (size_t)(i0 + lr) * Hn + k0 + lc);
    float4 bv4 = *(const float4*)(W + (size_t)(n0 + lr) * Hn + k0 + lc);
    As[lr][lc] = av.x; As[lr][lc+1] = av.y; As[lr][lc+2] = av.z; As[lr][lc+3] = av.w;
    Bs[lr][lc] = bv4.x; Bs[lr][lc+1] = bv4.y; Bs[lr][lc+2] = bv4.z; Bs[lr][lc+3] = bv4.w;
    __syncthreads();
#pragma unroll
    for (int kk = 0; kk < 16; ++kk) {
      float a[4], b[4];
#pragma unroll
      for (int ii = 0; ii < 4; ++ii) a[ii] = As[ty*4+ii][kk];
#pragma unroll
      for (int jj = 0; jj < 4; ++jj) b[jj] = Bs[tx*4+jj][kk];
#pragma unroll
      for (int ii = 0; ii < 4; ++ii)
#pragma unroll
        for (int jj = 0; jj < 4; ++jj) acc[ii][jj] += a[ii]*b[jj];
    }
    __syncthreads();
  }
#pragma unroll
  for (int ii = 0; ii < 4; ++ii) {
    int gi = i0 + ty*4 + ii;
#pragma unroll
    for (int jj = 0; jj < 4; ++jj) {
      int nn = n0 + tx*4 + jj;
      outp[(size_t)gi * Hn + nn] = acc[ii][jj] + bias[nn];
    }
  }
}

// ---------------- scores = q @ k^T / sqrt(H), lower-triangular tiles ---------
__global__ __launch_bounds__(256) void score_kernel(const float* __restrict__ q,
                                                    const float* __restrict__ k,
                                                    float* __restrict__ s) {
  int tj = blockIdx.x, ti = blockIdx.y, b = blockIdx.z;
  if (tj > ti) return;
  __shared__ float As[64][17];
  __shared__ float Bs[64][17];
  const float* qb = q + (size_t)b * Tn * Hn;
  const float* kb = k + (size_t)b * Tn * Hn;
  int i0 = ti * 64, j0 = tj * 64;
  int tid = threadIdx.x;
  int ty = tid >> 4, tx = tid & 15;
  int lr = tid >> 2, lc = (tid & 3) * 4;
  float acc[4][4];
#pragma unroll
  for (int a = 0; a < 4; ++a)
#pragma unroll
    for (int c = 0; c < 4; ++c) acc[a][c] = 0.0f;
  for (int k0 = 0; k0 < Hn; k0 += 16) {
    float4 av = *(const float4*)(qb + (size_t)(i0 + lr) * Hn + k0 + lc);
    float4 bv = *(const float4*)(kb + (size_t)(j0 + lr) * Hn + k0 + lc);
    As[lr][lc] = av.x; As[lr][lc+1] = av.y; As[lr][lc+2] = av.z; As[lr][lc+3] = av.w;
    Bs[lr][lc] = bv.x; Bs[lr][lc+1] = bv.y; Bs[lr][lc+2] = bv.z; Bs[lr][lc+3] = bv.w;
    __syncthreads();
#pragma unroll
    for (int kk = 0; kk < 16; ++kk) {
      float a[4], bb[4];
#pragma unroll
      for (int ii = 0; ii < 4; ++ii) a[ii] = As[ty*4+ii][kk];
#pragma unroll
      for (int jj = 0; jj < 4; ++jj) bb[jj] = Bs[tx*4+jj][kk];
#pragma unroll
      for (int ii = 0; ii < 4; ++ii)
#pragma unroll
        for (int jj = 0; jj < 4; ++jj) acc[ii][jj] += a[ii]*bb[jj];
    }
    __syncthreads();
  }
  const float scale = 0.04419417382415922f;  // 1/sqrt(512)
#pragma unroll
  for (int ii = 0; ii < 4; ++ii) {
    int gi = i0 + ty*4 + ii;
#pragma unroll
    for (int jj = 0; jj < 4; ++jj) {
      int gj = j0 + tx*4 + jj;
      s[(size_t)b*Tn*Tn + (size_t)gi*Tn + gj] = acc[ii][jj] * scale;
    }
  }
}

// ---------------- causal softmax in-place over row [0..i] --------------------
__global__ __launch_bounds__(256) void softmax_kernel(float* __restrict__ s) {
  int row = blockIdx.x;
  int b = row >> 11, i = row & 2047;
  float* p = s + (size_t)b*Tn*Tn + (size_t)i*Tn;
  int len = i + 1;
  int tid = threadIdx.x;
  __shared__ float redm[4];
  __shared__ float reds[4];
  float m = -1e30f;
  for (int j = tid; j < len; j += 256) m = fmaxf(m, p[j]);
#pragma unroll
  for (int off = 32; off > 0; off >>= 1) m = fmaxf(m, __shfl_down(m, off));
  if ((tid & 63) == 0) redm[tid >> 6] = m;
  __syncthreads();
  if (tid == 0) redm[0] = fmaxf(fmaxf(redm[0], redm[1]), fmaxf(redm[2], redm[3]));
  __syncthreads();
  m = redm[0];
  float sum = 0.0f;
  for (int j = tid; j < len; j += 256) {
    float e = __expf(p[j] - m);
    p[j] = e;
    sum += e;
  }
#pragma unroll
  for (int off = 32; off > 0; off >>= 1) sum += __shfl_down(sum, off);
  if ((tid & 63) == 0) reds[tid >> 6] = sum;
  __syncthreads();
  if (tid == 0) reds[0] = reds[0] + reds[1] + reds[2] + reds[3];
  __syncthreads();
  float inv = 1.0f / reds[0];
  for (int j = tid; j < len; j += 256) p[j] *= inv;
}

// ---------------- ctx = attn @ v  (causal, fp32 tiled 64x64) -----------------
__global__ __launch_bounds__(256) void ctx_kernel(const float* __restrict__ s,
                                                  const float* __restrict__ v,
                                                  float* __restrict__ ctx) {
  int te = blockIdx.x, ti = blockIdx.y, b = blockIdx.z;
  __shared__ float As[64][17];   // attn[i][j] chunk
  __shared__ float Bs[16][65];   // v[j][e] chunk
  int i0 = ti * 64, e0 = te * 64;
  int kmax = (ti + 1) * 64;
  int tid = threadIdx.x;
  int ty = tid >> 4, tx = tid & 15;
  float acc[4][4];
#pragma unroll
  for (int a = 0; a < 4; ++a)
#pragma unroll
    for (int c = 0; c < 4; ++c) acc[a][c] = 0.0f;
  int lr = tid >> 2, lc = (tid & 3) * 4;      // A-load: 64 rows x 16 cols
  int jr = tid >> 4, ec = (tid & 15) * 4;     // B-load: 16 rows x 64 cols
  for (int k0 = 0; k0 < kmax; k0 += 16) {
    int gi = i0 + lr;
    float4 av = *(const float4*)(s + (size_t)b*Tn*Tn + (size_t)gi*Tn + k0 + lc);
    As[lr][lc]   = (k0 + lc     <= gi) ? av.x : 0.0f;
    As[lr][lc+1] = (k0 + lc + 1 <= gi) ? av.y : 0.0f;
    As[lr][lc+2] = (k0 + lc + 2 <= gi) ? av.z : 0.0f;
    As[lr][lc+3] = (k0 + lc + 3 <= gi) ? av.w : 0.0f;
    float4 bv = *(const float4*)(v + (size_t)b*Tn*Hn + (size_t)(k0 + jr)*Hn + e0 + ec);
    Bs[jr][ec] = bv.x; Bs[jr][ec+1] = bv.y; Bs[jr][ec+2] = bv.z; Bs[jr][ec+3] = bv.w;
    __syncthreads();
#pragma unroll
    for (int kk = 0; kk < 16; ++kk) {
      float a[4], bb[4];
#pragma unroll
      for (int ii = 0; ii < 4; ++ii) a[ii] = As[ty*4+ii][kk];
#pragma unroll
      for (int jj = 0; jj < 4; ++jj) bb[jj] = Bs[kk][tx*4+jj];
#pragma unroll
      for (int ii = 0; ii < 4; ++ii)
#pragma unroll
        for (int jj = 0; jj < 4; ++jj) acc[ii][jj] += a[ii]*bb[jj];
    }
    __syncthreads();
  }
#pragma unroll
  for (int ii = 0; ii < 4; ++ii) {
    int gi = i0 + ty*4 + ii;
#pragma unroll
    for (int jj = 0; jj < 4; ++jj) {
      int ge = e0 + tx*4 + jj;
      ctx[(size_t)(b*Tn + gi) * Hn + ge] = acc[ii][jj];
    }
  }
}

// ---------------- logits = ctx_bf16 @ Wfc_bf16^T + bfc  (MFMA 16x16x32) ------
__global__ __launch_bounds__(256) void logits_kernel(const unsigned short* __restrict__ A,
                                                     const unsigned short* __restrict__ Bw,
                                                     const float* __restrict__ bias,
                                                     float* __restrict__ out) {
  __shared__ unsigned short a_lds[128 * 40];   // 128 rows, 32 cols padded to 40
  __shared__ unsigned short b_lds[128 * 40];
  int n0 = blockIdx.x * 128, m0 = blockIdx.y * 128;
  int tid = threadIdx.x;
  int wid = tid >> 6, lane = tid & 63;
  int wm = wid >> 1, wn = wid & 1;
  f32x4 acc[4][4];
#pragma unroll
  for (int mf = 0; mf < 4; ++mf)
#pragma unroll
    for (int nf = 0; nf < 4; ++nf) {
      acc[mf][nf][0] = 0.0f; acc[mf][nf][1] = 0.0f;
      acc[mf][nf][2] = 0.0f; acc[mf][nf][3] = 0.0f;
    }
  int kcol = (lane >> 4) * 8;
  int rbase = lane & 15;
  for (int k0 = 0; k0 < 512; k0 += 32) {
#pragma unroll
    for (int sidx = 0; sidx < 2; ++sidx) {
      int slot = tid + sidx * 256;              // 512 slots: 128 rows x 4 (8-col groups)
      int row = slot >> 2, c8 = (slot & 3) * 8;
      uint4 av = *(const uint4*)(A  + (size_t)(m0 + row) * 512 + k0 + c8);
      *(uint4*)&a_lds[row * 40 + c8] = av;
      uint4 bv = *(const uint4*)(Bw + (size_t)(n0 + row) * 512 + k0 + c8);
      *(uint4*)&b_lds[row * 40 + c8] = bv;
    }
    __syncthreads();
    bf16x8 af[4], bf[4];
#pragma unroll
    for (int mf = 0; mf < 4; ++mf)
      af[mf] = *(const bf16x8*)&a_lds[(wm*64 + mf*16 + rbase) * 40 + kcol];
#pragma unroll
    for (int nf = 0; nf < 4; ++nf)
      bf[nf] = *(const bf16x8*)&b_lds[(wn*64 + nf*16 + rbase) * 40 + kcol];
#pragma unroll
    for (int mf = 0; mf < 4; ++mf)
#pragma unroll
      for (int nf = 0; nf < 4; ++nf)
        acc[mf][nf] = __builtin_amdgcn_mfma_f32_16x16x32_bf16(af[mf], bf[nf], acc[mf][nf], 0, 0, 0);
    __syncthreads();
  }
  int rgrp = (lane >> 4) * 4;
#pragma unroll
  for (int mf = 0; mf < 4; ++mf)
#pragma unroll
    for (int nf = 0; nf < 4; ++nf) {
      int col = n0 + wn*64 + nf*16 + (lane & 15);
      float bc = bias[col];
#pragma unroll
      for (int i2 = 0; i2 < 4; ++i2) {
        int row = m0 + wm*64 + mf*16 + rgrp + i2;
        out[(size_t)row * Vn + col] = acc[mf][nf][i2] + bc;
      }
    }
}

extern "C" void kernel_launch(void* const* d_in, const int* in_sizes, int n_in,
                              void* d_out, int out_size, void* d_ws, size_t ws_size,
                              hipStream_t stream) {
  const int*   x   = (const int*)d_in[0];
  const float* emb = (const float*)d_in[1];
  const float* Wih = (const float*)d_in[2];
  const float* Whh = (const float*)d_in[3];
  const float* bih = (const float*)d_in[4];
  const float* bhh = (const float*)d_in[5];
  const float* Wq  = (const float*)d_in[6];
  const float* bq  = (const float*)d_in[7];
  const float* Wk  = (const float*)d_in[8];
  const float* bk  = (const float*)d_in[9];
  const float* Wv  = (const float*)d_in[10];
  const float* bv  = (const float*)d_in[11];
  const float* Wfc = (const float*)d_in[12];
  const float* bfc = (const float*)d_in[13];
  float* out = (float*)d_out;

  char* ws = (char*)d_ws;
  float* hs  = (float*)(ws);                                  // 16,777,216 B
  float* q   = (float*)(ws + 16777216);                       // 16,777,216 B
  float* k   = (float*)(ws + 33554432);                       // 16,777,216 B
  float* v   = (float*)(ws + 50331648);                       // 16,777,216 B
  float* ctx = (float*)(ws + 67108864);                       // 16,777,216 B
  unsigned short* ctxb = (unsigned short*)(ws + 83886080);    //  8,388,608 B
  unsigned short* wfcb = (unsigned short*)(ws + 92274688);    // 32,768,000 B
  // ws total: ~125 MB

  // d_out (1,048,576,000 B) doubles as scratch: scores + xg + tagged-h, all
  // fully consumed before logits_kernel overwrites the whole buffer.
  float* scores = out;                                        // [0, 67,108,864)
  float* xg = (float*)((char*)d_out + 67108864);              // [67,108,864, 117,440,512)
  unsigned long long* th = (unsigned long long*)((char*)d_out + 117440512);  // 33,554,432 B

  hipMemsetAsync(th, 0, (size_t)Tn * 2048 * 8, stream);       // clear tags (replay-safe)
  cvt_bf16_kernel<<<16000, 256, 0, stream>>>(Wfc, wfcb);                       // 16,384,000 elems
  xg_kernel<<<dim3(24, 128), 256, 0, stream>>>(x, emb, Wih, bih, xg);
  gru_kernel<<<64, 256, 0, stream>>>(Whh, bhh, xg, hs, th);
  qkv_kernel<<<dim3(24, 128), 256, 0, stream>>>(hs, Wq, bq, Wk, bk, Wv, bv, q, k, v);
  score_kernel<<<dim3(32, 32, Bn), 256, 0, stream>>>(q, k, scores);
  softmax_kernel<<<BT, 256, 0, stream>>>(scores);
  ctx_kernel<<<dim3(8, 32, Bn), 256, 0, stream>>>(scores, v, ctx);
  cvt_bf16_kernel<<<4096, 256, 0, stream>>>(ctx, ctxb);                        // 4,194,304 elems
  logits_kernel<<<dim3(250, 64), 256, 0, stream>>>(ctxb, wfcb, bfc, out);
}